// Round 8
// baseline (274.601 us; speedup 1.0000x reference)
//
#include <hip/hip_runtime.h>
#include <stdint.h>

#define BB   8
#define NN   2048
#define FIN  256
#define FOUT 128

using short8 = __attribute__((ext_vector_type(8))) short;
using f32x4  = __attribute__((ext_vector_type(4))) float;

__device__ __forceinline__ unsigned short rbf(float f) {
    return (unsigned short)((__float_as_uint(f) + 0x8000u) >> 16);
}

// Calibration: 2 probe MFMAs read off the true (row,col) label of each
// accumulator element (validated round 4). Epilogues index by these labels.
__device__ __forceinline__ void mfma_calib(int m, int quad, int* Mlab, int* Nlab) {
    short8 pa1, pb1, pa2, pb2;
    const short one = (short)0x3F80;            // bf16 1.0
    const short mb  = (short)rbf((float)m);     // bf16 m (exact, m<16)
#pragma unroll
    for (int j = 0; j < 8; ++j) { pa1[j] = 0; pa2[j] = 0; pb1[j] = mb; pb2[j] = one; }
    if (quad == 0) { pa1[0] = one; pa2[0] = mb; }
    f32x4 zz = {0.f, 0.f, 0.f, 0.f};
    f32x4 c1 = __builtin_amdgcn_mfma_f32_16x16x32_bf16(pa1, pb1, zz, 0, 0, 0);
    f32x4 c2 = __builtin_amdgcn_mfma_f32_16x16x32_bf16(pa2, pb2, zz, 0, 0, 0);
#pragma unroll
    for (int r = 0; r < 4; ++r) {
        Nlab[r] = ((int)c1[r]) & 15;
        Mlab[r] = ((int)c2[r]) & 15;
    }
}

// ---------------- W[256][128] fp32 -> wt[128][256] bf16 (W^T) --------------
__global__ __launch_bounds__(256) void gat_wt(const float* __restrict__ W,
                                              unsigned short* __restrict__ wt) {
    const int g  = blockIdx.x * 256 + threadIdx.x;
    const int k  = g >> 5;
    const int o4 = (g & 31) << 2;
    float4 wv = *(const float4*)(W + (k << 7) + o4);
    wt[((o4 + 0) << 8) + k] = rbf(wv.x);
    wt[((o4 + 1) << 8) + k] = rbf(wv.y);
    wt[((o4 + 2) << 8) + k] = rbf(wv.z);
    wt[((o4 + 3) << 8) + k] = rbf(wv.w);
}

// ---------------- stage 1: h = x@W via MFMA (16 rows/block) ----------------
__global__ __launch_bounds__(256) void gat_h3(
        const float* __restrict__ x, const unsigned short* __restrict__ wt,
        const float* __restrict__ a, unsigned short* __restrict__ ht,
        float* __restrict__ f1, float* __restrict__ f2) {
    __shared__ unsigned short xs[16][264];
    __shared__ float hs[16][132];
    const int bk   = blockIdx.x;
    const int R0   = bk << 4;
    const int b    = R0 >> 11;
    const int il0  = R0 & (NN - 1);
    const int tid  = threadIdx.x;
    const int w    = tid >> 6;
    const int lane = tid & 63;
    const int m    = lane & 15;
    const int quad = lane >> 4;

#pragma unroll
    for (int rr = 0; rr < 4; ++rr) {
        const int row = (w << 2) + rr;
        float4 xv = *(const float4*)(x + (size_t)(R0 + row) * FIN + (lane << 2));
        ushort4 c4;
        c4.x = rbf(xv.x); c4.y = rbf(xv.y); c4.z = rbf(xv.z); c4.w = rbf(xv.w);
        *(ushort4*)(&xs[row][lane << 2]) = c4;
    }
    int Mlab[4], Nlab[4];
    mfma_calib(m, quad, Mlab, Nlab);
    __syncthreads();

    f32x4 zz = {0.f, 0.f, 0.f, 0.f};
    f32x4 acc[2] = {zz, zz};
#pragma unroll
    for (int kc = 0; kc < 8; ++kc) {
        const int k0 = (kc << 5) + (quad << 3);
        short8 av = *(const short8*)(&xs[m][k0]);
#pragma unroll
        for (int t = 0; t < 2; ++t) {
            const int ot = (w << 1) + t;
            short8 bw = *(const short8*)(wt + (((ot << 4) + m) << 8) + k0);
            acc[t] = __builtin_amdgcn_mfma_f32_16x16x32_bf16(av, bw, acc[t], 0, 0, 0);
        }
    }
#pragma unroll
    for (int t = 0; t < 2; ++t)
#pragma unroll
        for (int r = 0; r < 4; ++r)
            hs[Mlab[r]][(((w << 1) + t) << 4) + Nlab[r]] = acc[t][r];
    __syncthreads();

    {
        const int i   = tid >> 4;
        const int seg = tid & 15;
        const int o0  = seg << 3;
        float s1 = 0.f, s2 = 0.f;
#pragma unroll
        for (int e = 0; e < 8; ++e) {
            float hv = hs[i][o0 + e];
            s1 = fmaf(hv, a[o0 + e], s1);
            s2 = fmaf(hv, a[FOUT + o0 + e], s2);
        }
        s1 += __shfl_xor(s1, 1); s1 += __shfl_xor(s1, 2);
        s1 += __shfl_xor(s1, 4); s1 += __shfl_xor(s1, 8);
        s2 += __shfl_xor(s2, 1); s2 += __shfl_xor(s2, 2);
        s2 += __shfl_xor(s2, 4); s2 += __shfl_xor(s2, 8);
        if (seg == 0) { f1[R0 + i] = s1; f2[R0 + i] = s2; }
    }
    {
        const int o  = tid >> 1;
        const int i8 = (tid & 1) << 3;
        short8 hv;
#pragma unroll
        for (int e = 0; e < 8; ++e) hv[e] = (short)rbf(hs[i8 + e][o]);
        *(short8*)(ht + ((size_t)((b << 7) + o) << 11) + il0 + i8) = hv;
    }
}

// ---------------- stage 2: fused masked-softmax attention ------------------
// Block = 64 rows (256 blocks, 1/CU); 4 waves split j into quarters; each
// wave carries FOUR P-fragment row-sets sharing one hf B-fragment set ->
// ht re-read bytes halved again vs R7 (total loads ~272 MB: adj 134 + ht 134).
// Epilogue: rotating-region 4-phase LDS combine (disjoint regions per phase).
__global__ __launch_bounds__(256, 1) void gat_s5(
        const int* __restrict__ adj, const unsigned short* __restrict__ ht,
        const float* __restrict__ f1, const float* __restrict__ f2,
        float* __restrict__ out) {
    const int bk   = blockIdx.x;        // 0..255
    const int b    = bk & 7;            // batch fastest -> per-XCD L2 locality
    const int i0   = (bk >> 3) << 6;    // 64 rows per block
    const int tid  = threadIdx.x;
    const int w    = tid >> 6;          // j-quarter
    const int lane = tid & 63;
    const int m    = lane & 15;
    const int quad = lane >> 4;

    __shared__ float accb[64][132];     // 33.8 KB, used only after the j-loop
    __shared__ float sbuf[4][4][16];

    int Mlab[4], Nlab[4];
    mfma_calib(m, quad, Mlab, Nlab);

    const int gi0 = (b << 11) + i0;
    float f1v[4];
    const int* adjr[4];
#pragma unroll
    for (int g = 0; g < 4; ++g) {
        f1v[g]  = f1[gi0 + (g << 4) + m];
        adjr[g] = adj + ((size_t)(gi0 + (g << 4) + m) << 11);
    }
    const float* f2b = f2 + (b << 11);
    const unsigned short* htb = ht + ((size_t)b << 18);

    f32x4 zz = {0.f, 0.f, 0.f, 0.f};
    f32x4 acc[4][8];
#pragma unroll
    for (int g = 0; g < 4; ++g)
#pragma unroll
        for (int t = 0; t < 8; ++t) acc[g][t] = zz;
    float sp[4] = {0.f, 0.f, 0.f, 0.f};

    const int jb = (w << 9) + (quad << 3);
    for (int c = 0; c < 16; ++c) {
        const int j0 = jb + (c << 5);
        short8 hf[8];
#pragma unroll
        for (int ot = 0; ot < 8; ++ot)
            hf[ot] = *(const short8*)(htb + ((size_t)((ot << 4) + m) << 11) + j0);

        float4 fa = *(const float4*)(f2b + j0);
        float4 fb = *(const float4*)(f2b + j0 + 4);
        float fm[8] = {fa.x, fa.y, fa.z, fa.w, fb.x, fb.y, fb.z, fb.w};

#pragma unroll
        for (int g = 0; g < 4; ++g) {
            int4 a0 = *(const int4*)(adjr[g] + j0);
            int4 a1 = *(const int4*)(adjr[g] + j0 + 4);
            int am[8] = {a0.x, a0.y, a0.z, a0.w, a1.x, a1.y, a1.z, a1.w};
            const float f1r = f1v[g];
            float p[8];
#pragma unroll
            for (int u = 0; u < 8; ++u) {
                float e = f1r + fm[u];
                p[u] = (am[u] > 0) ? __expf(fmaxf(e, 0.2f * e)) : 0.f;
            }
            sp[g] += ((p[0] + p[1]) + (p[2] + p[3])) + ((p[4] + p[5]) + (p[6] + p[7]));
            short8 pf;
#pragma unroll
            for (int u = 0; u < 8; ++u) pf[u] = (short)rbf(p[u]);
#pragma unroll
            for (int ot = 0; ot < 8; ++ot)
                acc[g][ot] = __builtin_amdgcn_mfma_f32_16x16x32_bf16(pf, hf[ot], acc[g][ot], 0, 0, 0);
        }
    }

    // per-row denominators: quad-reduce, stash per (wave, set)
#pragma unroll
    for (int g = 0; g < 4; ++g) {
        float v = sp[g];
        v += __shfl_xor(v, 16); v += __shfl_xor(v, 32);
        if (lane < 16) sbuf[w][g][lane] = v;
    }

    // rotating-region combine: phase p, wave w handles region g=(w+p)&3
    // (rows g*16..g*16+15). Phase 0 writes, phases 1-3 add. Regions disjoint
    // per phase -> all 4 waves active, no serialization.
#pragma unroll
    for (int p = 0; p < 4; ++p) {
        const int g = (w + p) & 3;
        if (p == 0) {
#pragma unroll
            for (int ot = 0; ot < 8; ++ot)
#pragma unroll
                for (int r = 0; r < 4; ++r)
                    accb[(g << 4) + Mlab[r]][(ot << 4) + Nlab[r]] = acc[g][ot][r];
        } else {
#pragma unroll
            for (int ot = 0; ot < 8; ++ot)
#pragma unroll
                for (int r = 0; r < 4; ++r)
                    accb[(g << 4) + Mlab[r]][(ot << 4) + Nlab[r]] += acc[g][ot][r];
        }
        __syncthreads();
    }

    // normalize + ELU + store: thread -> (row = tid>>2, 32-o segment)
    {
        const int row = tid >> 2;
        const int o0  = (tid & 3) << 5;
        const int g   = row >> 4;
        const int mm  = row & 15;
        const float s = (sbuf[0][g][mm] + sbuf[1][g][mm]) +
                        (sbuf[2][g][mm] + sbuf[3][g][mm]);
        const float inv = 1.0f / s;
        float* orow = out + (((size_t)gi0 + row) << 7) + o0;
#pragma unroll
        for (int v4 = 0; v4 < 8; ++v4) {
            float4 rv;
            float y;
            y = accb[row][o0 + 4 * v4 + 0] * inv; rv.x = y > 0.f ? y : expm1f(y);
            y = accb[row][o0 + 4 * v4 + 1] * inv; rv.y = y > 0.f ? y : expm1f(y);
            y = accb[row][o0 + 4 * v4 + 2] * inv; rv.z = y > 0.f ? y : expm1f(y);
            y = accb[row][o0 + 4 * v4 + 3] * inv; rv.w = y > 0.f ? y : expm1f(y);
            *(float4*)(orow + 4 * v4) = rv;
        }
    }
}

extern "C" void kernel_launch(void* const* d_in, const int* in_sizes, int n_in,
                              void* d_out, int out_size, void* d_ws, size_t ws_size,
                              hipStream_t stream) {
    const float* x   = nullptr;
    const int*   adj = nullptr;
    const float* W   = nullptr;
    const float* a   = nullptr;
    for (int i = 0; i < n_in; ++i) {
        const long s = in_sizes[i];
        if      (s == (long)BB * NN * NN)  adj = (const int*)d_in[i];
        else if (s == (long)BB * NN * FIN) x   = (const float*)d_in[i];
        else if (s == (long)FIN * FOUT)    W   = (const float*)d_in[i];
        else if (s == 2L * FOUT)           a   = (const float*)d_in[i];
    }
    if (!x)   x   = (const float*)d_in[0];
    if (!adj) adj = (const int*)d_in[1];
    if (!W)   W   = (const float*)d_in[2];
    if (!a)   a   = (const float*)d_in[3];
    float* out = (float*)d_out;

    unsigned short* wt = (unsigned short*)d_ws;            // 64 KB  W^T bf16
    unsigned short* ht = wt + 32768;                       // 4 MB   h^T bf16 [B][128][N]
    float* f1 = (float*)(ht + (size_t)BB * NN * FOUT);     // 64 KB
    float* f2 = f1 + BB * NN;                              // 64 KB

    hipLaunchKernelGGL(gat_wt, dim3(32),   dim3(256), 0, stream, W, wt);
    hipLaunchKernelGGL(gat_h3, dim3(1024), dim3(256), 0, stream, x, wt, a, ht, f1, f2);
    hipLaunchKernelGGL(gat_s5, dim3(256),  dim3(256), 0, stream, adj, ht, f1, f2, out);
}